// Round 1
// baseline (13010.419 us; speedup 1.0000x reference)
//
#include <hip/hip_runtime.h>
#include <cstdint>

// MessagePassing_70901320122389 — fp32 baseline, fully fused per conv.
// N=20000 nodes, E=320000 edges. CS=64, CV=32, CM=96, WN=192, FCH=64.

#define CS 64
#define CV 32
#define CM 96
#define WN 192
#define FCH 64

__device__ __forceinline__ float siluf(float x){ return x / (1.f + __expf(-x)); }

constexpr float INV8       = 0.125f;                  // 1/sqrt(64)
constexpr float INV_SQRT32 = 0.17677669529663687f;    // 1/sqrt(32)
constexpr float INV_SQRT96 = 0.10206207261596575f;    // 1/sqrt(96)
constexpr float INV_SQRT3  = 0.5773502691896258f;     // 1/sqrt(3)

// ---------------- degree ----------------
__global__ void deg_kernel(const int* __restrict__ edst, float* __restrict__ deg, int E){
    int e = blockIdx.x*blockDim.x + threadIdx.x;
    if (e < E) atomicAdd(&deg[edst[e]], 1.0f);
}

__global__ void isd_kernel(float* __restrict__ d, int n){
    int i = blockIdx.x*blockDim.x + threadIdx.x;
    if (i < n) d[i] = rsqrtf(d[i]);   // deg >= 1 guaranteed (self loops in first N edges)
}

// ---------------- node pre-transform (f_s, sc_s, f_v, sc_v) ----------------
// one thread per (node, output-channel). OS = sc_s output cols (96 conv1, 64 conv2).
template<int OS>
__global__ void node_pre(const float* __restrict__ s, int ss,
                         const float* __restrict__ v, int vs,
                         const float* __restrict__ attr,
                         const float* __restrict__ Wl1s, const float* __restrict__ Wscs,
                         const float* __restrict__ Wl1v, const float* __restrict__ Wscv,
                         float* __restrict__ f_s, float* __restrict__ sc_s,
                         float* __restrict__ f_v, float* __restrict__ sc_v, int n_nodes)
{
    constexpr int TOT = 64 + OS + 96 + 96;
    int t = blockIdx.x*blockDim.x + threadIdx.x;
    if (t >= n_nodes*TOT) return;
    int n = t / TOT, r = t - n*TOT;
    float a = attr[n];
    const float* srow = s + (size_t)n*ss;
    const float* vrow = v + (size_t)n*vs;

    if (r < 64 + OS){
        float acc = 0.f;
        if (r < 64){
            const float* col = Wl1s + r;
            #pragma unroll 8
            for (int k = 0; k < 64; ++k) acc += srow[k]*col[k*64];
            f_s[(size_t)n*64 + r] = acc * a * INV8;
        } else {
            int j = r - 64;
            const float* col = Wscs + j;
            #pragma unroll 8
            for (int k = 0; k < 64; ++k) acc += srow[k]*col[k*OS];
            sc_s[(size_t)n*OS + j] = acc * a * INV8;
        }
    } else {
        int q = r - (64 + OS);
        bool first = (q < 96);
        if (!first) q -= 96;
        int w = q/3, c = q - 3*w;
        const float* W = first ? Wl1v : Wscv;
        float acc = 0.f;
        #pragma unroll 8
        for (int u = 0; u < 32; ++u) acc += vrow[u*3 + c]*W[u*32 + w];
        float* op = (first ? f_v : sc_v) + (size_t)n*96 + q;
        *op = acc * a * INV_SQRT32;
    }
}

// ---------------- fused edge kernel ----------------
// One thread per edge: per-edge 2-layer MLP with weights (transposed) in LDS,
// read as wave-uniform float4 broadcasts; messages consumed into atomics.
__global__ __launch_bounds__(256, 2) void edge_conv(
    const float* __restrict__ f_s, const float* __restrict__ f_v,
    const int* __restrict__ esrc, const int* __restrict__ edst,
    const float* __restrict__ eattr, const float* __restrict__ escal,
    const float* __restrict__ Wfa, const float* __restrict__ Wfb,
    float* __restrict__ agg_s, float* __restrict__ agg_v, int E)
{
    __shared__ __align__(16) float lds[CS*FCH + WN*FCH];  // 16384 floats = 64 KB
    const int tid = threadIdx.x;
    // WfaT[j][k] = Wfa[k][j]  (64x64)
    for (int i = tid; i < FCH*CS; i += 256){ int k = i >> 6, j = i & 63; lds[j*FCH + k] = Wfa[i]; }
    // WfbT[o][k] = Wfb[k][o]  (192 rows of 64)
    for (int i = tid; i < FCH*WN; i += 256){ int k = i / WN, o = i - k*WN; lds[CS*FCH + o*FCH + k] = Wfb[i]; }
    __syncthreads();

    const int e = blockIdx.x*256 + tid;
    if (e >= E) return;

    // load this edge's scalars into registers
    float4 es[16];
    {
        const float4* p = reinterpret_cast<const float4*>(escal + (size_t)e*CS);
        #pragma unroll
        for (int k = 0; k < 16; ++k) es[k] = p[k];
    }

    // layer 1: h = silu(es @ Wfa / 8)   (fully unrolled so h stays in VGPRs)
    float h[FCH];
    #pragma unroll
    for (int j = 0; j < FCH; ++j){
        const float4* wr = reinterpret_cast<const float4*>(&lds[j*FCH]);
        float ax=0.f, ay=0.f, az=0.f, aw=0.f;
        #pragma unroll
        for (int k = 0; k < 16; ++k){
            float4 w = wr[k];
            ax += es[k].x*w.x; ay += es[k].y*w.y; az += es[k].z*w.z; aw += es[k].w*w.w;
        }
        float x = ((ax+ay)+(az+aw)) * INV8;
        h[j] = siluf(x);
    }

    const int src = esrc[e], dst = edst[e];
    const float* ep = eattr + (size_t)e*4;
    const float eas = ep[0], ev0 = ep[1], ev1 = ep[2], ev2 = ep[3];
    const float* fsrow = f_s + (size_t)src*CS;
    const float* fvrow = f_v + (size_t)src*(CV*3);
    float* as_ = agg_s + (size_t)dst*CM;
    float* av_ = agg_v + (size_t)dst*(CM*3);
    const float* wfb = &lds[CS*FCH];

    auto wdot = [&](int o) -> float {
        const float4* wr = reinterpret_cast<const float4*>(&wfb[o*FCH]);
        float ax=0.f, ay=0.f, az=0.f, aw=0.f;
        #pragma unroll
        for (int k = 0; k < 16; ++k){
            float4 w = wr[k];
            ax += h[4*k+0]*w.x; ay += h[4*k+1]*w.y; az += h[4*k+2]*w.z; aw += h[4*k+3]*w.w;
        }
        return ((ax+ay)+(az+aw)) * INV8;
    };

    // w00: mid_s[0:64] = w00 * gs * ea_s
    #pragma unroll 2
    for (int o = 0; o < 64; ++o){
        float w = wdot(o);
        atomicAdd(as_ + o, w * fsrow[o] * eas);
    }
    // w01: mid_v[0:64][c] = (w01*gs) * ea_v[c]
    #pragma unroll 2
    for (int o = 0; o < 64; ++o){
        float w = wdot(64 + o);
        float g = w * fsrow[o];
        atomicAdd(av_ + o*3+0, g*ev0);
        atomicAdd(av_ + o*3+1, g*ev1);
        atomicAdd(av_ + o*3+2, g*ev2);
    }
    // w10: mid_v[64:96][c] = w10 * gv[u][c] * ea_s
    #pragma unroll 2
    for (int u = 0; u < 32; ++u){
        float w = wdot(128 + u);
        float wss = w * eas;
        float* p = av_ + (64+u)*3;
        atomicAdd(p+0, wss*fvrow[u*3+0]);
        atomicAdd(p+1, wss*fvrow[u*3+1]);
        atomicAdd(p+2, wss*fvrow[u*3+2]);
    }
    // w11: mid_s[64:96] = w11 * (gv . ea_v) / sqrt(3)
    #pragma unroll 2
    for (int u = 0; u < 32; ++u){
        float w = wdot(160 + u);
        float dv = fvrow[u*3+0]*ev0 + fvrow[u*3+1]*ev1 + fvrow[u*3+2]*ev2;
        atomicAdd(as_ + 64 + u, w * dv * INV_SQRT3);
    }
}

// ---------------- node post (conv1): produce gated g_s, g_v ----------------
__global__ void node_post1(const float* __restrict__ agg_s, const float* __restrict__ agg_v,
                           const float* __restrict__ isd, const float* __restrict__ attr,
                           const float* __restrict__ sc_s, const float* __restrict__ sc_v,
                           const float* __restrict__ W2s, const float* __restrict__ W2v,
                           const float* __restrict__ W3,
                           float* __restrict__ g_s, float* __restrict__ g_v, int n_nodes)
{
    const int n = blockIdx.x;
    const int t = threadIdx.x;   // 192 threads
    __shared__ float asd[96], avd[288], hsl[96];
    float is = isd[n];
    if (t < 96) asd[t] = agg_s[(size_t)n*96 + t] * is;
    for (int i = t; i < 288; i += 192) avd[i] = agg_v[(size_t)n*288 + i] * is;
    __syncthreads();

    float a = attr[n];
    float ang = 0.f;
    #pragma unroll 8
    for (int u = 0; u < 96; ++u) ang += asd[u]*W3[u];
    ang *= 0.1f * a * INV_SQRT96;
    float cc_ = cosf(ang), si_ = sinf(ang);

    float hv = 0.f;
    if (t < 96){
        float acc = 0.f;
        #pragma unroll 8
        for (int u = 0; u < 96; ++u) acc += asd[u]*W2s[u*96 + t];
        float os = acc * a * INV_SQRT96;
        hsl[t] = cc_*sc_s[(size_t)n*96 + t] + si_*os;
    } else {
        int q = t - 96; int w = q/3, c = q - 3*w;
        float acc = 0.f;
        #pragma unroll 8
        for (int u = 0; u < 96; ++u) acc += avd[u*3 + c]*W2v[u*32 + w];
        float ov = acc * a * INV_SQRT96;
        hv = cc_*sc_v[(size_t)n*96 + q] + si_*ov;
    }
    __syncthreads();

    if (t < 64){
        g_s[(size_t)n*64 + t] = siluf(hsl[t]);
    } else if (t >= 96){
        int q = t - 96; int w = q/3;
        float sg = 1.f / (1.f + __expf(-hsl[64 + w]));
        g_v[(size_t)n*96 + q] = sg * hv;
    }
}

// ---------------- node post (conv2): write final output ----------------
__global__ void node_post2(const float* __restrict__ agg_s, const float* __restrict__ agg_v,
                           const float* __restrict__ isd, const float* __restrict__ attr,
                           const float* __restrict__ sc_s, const float* __restrict__ sc_v,
                           const float* __restrict__ W2s, const float* __restrict__ W2v,
                           const float* __restrict__ W3,
                           float* __restrict__ out, int n_nodes)
{
    const int n = blockIdx.x;
    const int t = threadIdx.x;   // 192 threads (160 active in compute)
    __shared__ float asd[96], avd[288];
    float is = isd[n];
    if (t < 96) asd[t] = agg_s[(size_t)n*96 + t] * is;
    for (int i = t; i < 288; i += 192) avd[i] = agg_v[(size_t)n*288 + i] * is;
    __syncthreads();

    float a = attr[n];
    float ang = 0.f;
    #pragma unroll 8
    for (int u = 0; u < 96; ++u) ang += asd[u]*W3[u];
    ang *= 0.1f * a * INV_SQRT96;
    float cc_ = cosf(ang), si_ = sinf(ang);

    if (t < 64){
        float acc = 0.f;
        #pragma unroll 8
        for (int u = 0; u < 96; ++u) acc += asd[u]*W2s[u*64 + t];
        float os = acc * a * INV_SQRT96;
        out[(size_t)n*160 + t] = cc_*sc_s[(size_t)n*64 + t] + si_*os;
    } else if (t < 160){
        int q = t - 64; int w = q/3, c = q - 3*w;
        float acc = 0.f;
        #pragma unroll 8
        for (int u = 0; u < 96; ++u) acc += avd[u*3 + c]*W2v[u*32 + w];
        float ov = acc * a * INV_SQRT96;
        out[(size_t)n*160 + 64 + q] = cc_*sc_v[(size_t)n*96 + q] + si_*ov;
    }
}

// ---------------- launch ----------------
extern "C" void kernel_launch(void* const* d_in, const int* in_sizes, int n_in,
                              void* d_out, int out_size, void* d_ws, size_t ws_size,
                              hipStream_t stream)
{
    const float* nf    = (const float*)d_in[0];
    const float* nattr = (const float*)d_in[1];
    const int*   esrc  = (const int*)  d_in[2];
    const int*   edst  = (const int*)  d_in[3];
    const float* eattr = (const float*)d_in[4];
    const float* escal = (const float*)d_in[5];
    const float* p1_sc_s = (const float*)d_in[6];
    const float* p1_sc_v = (const float*)d_in[7];
    const float* p1_l1_s = (const float*)d_in[8];
    const float* p1_l1_v = (const float*)d_in[9];
    const float* p1_fa   = (const float*)d_in[10];
    const float* p1_fb   = (const float*)d_in[11];
    const float* p1_l2_s = (const float*)d_in[12];
    const float* p1_l2_v = (const float*)d_in[13];
    const float* p1_l3   = (const float*)d_in[14];
    const float* p2_sc_s = (const float*)d_in[15];
    const float* p2_sc_v = (const float*)d_in[16];
    const float* p2_l1_s = (const float*)d_in[17];
    const float* p2_l1_v = (const float*)d_in[18];
    const float* p2_fa   = (const float*)d_in[19];
    const float* p2_fb   = (const float*)d_in[20];
    const float* p2_l2_s = (const float*)d_in[21];
    const float* p2_l2_v = (const float*)d_in[22];
    const float* p2_l3   = (const float*)d_in[23];

    const int N = in_sizes[1];   // node_attr is (N,1)
    const int E = in_sizes[2];   // edge_src is (E,)

    float* ws = (float*)d_ws;
    size_t o_isd  = 0;
    size_t o_fs   = o_isd  + (size_t)N;
    size_t o_fv   = o_fs   + (size_t)N*64;
    size_t o_scs  = o_fv   + (size_t)N*96;
    size_t o_scv  = o_scs  + (size_t)N*96;
    size_t o_aggs = o_scv  + (size_t)N*96;
    size_t o_aggv = o_aggs + (size_t)N*96;    // agg_s,agg_v contiguous (single memset)
    size_t o_gs   = o_aggv + (size_t)N*288;
    size_t o_gv   = o_gs   + (size_t)N*64;
    // total = N*897 floats ≈ 71.8 MB — must fit in ws

    float* isd  = ws + o_isd;
    float* fs   = ws + o_fs;
    float* fv   = ws + o_fv;
    float* scs  = ws + o_scs;
    float* scv  = ws + o_scv;
    float* aggs = ws + o_aggs;
    float* aggv = ws + o_aggv;
    float* gs   = ws + o_gs;
    float* gv   = ws + o_gv;

    // degree -> inv sqrt
    hipMemsetAsync(isd, 0, (size_t)N*sizeof(float), stream);
    deg_kernel<<<(E+255)/256, 256, 0, stream>>>(edst, isd, E);
    isd_kernel<<<(N+255)/256, 256, 0, stream>>>(isd, N);

    // ---- conv1 ----
    hipMemsetAsync(aggs, 0, (size_t)N*384*sizeof(float), stream);
    {
        int tot = N*352;  // 64 + 96 + 96 + 96
        node_pre<96><<<(tot+255)/256, 256, 0, stream>>>(nf, 160, nf+64, 160, nattr,
            p1_l1_s, p1_sc_s, p1_l1_v, p1_sc_v, fs, scs, fv, scv, N);
    }
    edge_conv<<<(E+255)/256, 256, 0, stream>>>(fs, fv, esrc, edst, eattr, escal,
                                               p1_fa, p1_fb, aggs, aggv, E);
    node_post1<<<N, 192, 0, stream>>>(aggs, aggv, isd, nattr, scs, scv,
                                      p1_l2_s, p1_l2_v, p1_l3, gs, gv, N);

    // ---- conv2 ----
    hipMemsetAsync(aggs, 0, (size_t)N*384*sizeof(float), stream);
    {
        int tot = N*320;  // 64 + 64 + 96 + 96
        node_pre<64><<<(tot+255)/256, 256, 0, stream>>>(gs, 64, gv, 96, nattr,
            p2_l1_s, p2_sc_s, p2_l1_v, p2_sc_v, fs, scs, fv, scv, N);
    }
    edge_conv<<<(E+255)/256, 256, 0, stream>>>(fs, fv, esrc, edst, eattr, escal,
                                               p2_fa, p2_fb, aggs, aggv, E);
    node_post2<<<N, 192, 0, stream>>>(aggs, aggv, isd, nattr, scs, scv,
                                      p2_l2_s, p2_l2_v, p2_l3, (float*)d_out, N);
}

// Round 3
// 1595.313 us; speedup vs baseline: 8.1554x; 8.1554x over previous
//
#include <hip/hip_runtime.h>
#include <hip/hip_fp16.h>
#include <cstdint>

// MessagePassing — sorted-edge, atomic-free aggregation.
// N=20000, E=320000. CS=64, CV=32, CM=96, WN=192, FCH=64.

#define CS 64
#define CV 32
#define CM 96
#define WN 192
#define FCH 64

__device__ __forceinline__ float siluf(float x){ return x / (1.f + __expf(-x)); }

constexpr float INV8       = 0.125f;
constexpr float INV_SQRT32 = 0.17677669529663687f;
constexpr float INV_SQRT96 = 0.10206207261596575f;
constexpr float INV_SQRT3  = 0.5773502691896258f;

// ---------------- histogram of edge_dst ----------------
__global__ void hist_kernel(const int* __restrict__ edst, int* __restrict__ cnt, int E){
    int e = blockIdx.x*blockDim.x + threadIdx.x;
    if (e < E) atomicAdd(&cnt[edst[e]], 1);
}

// ---------------- single-block exclusive scan over N counts ----------------
__global__ void scan_kernel(const int* __restrict__ cnt, int* __restrict__ row_start,
                            int* __restrict__ cursor, int n, int E){
    __shared__ int part[1024];
    const int t = threadIdx.x;            // 1024 threads
    const int C = (n + 1023) / 1024;      // elems per thread (20 for N=20000)
    int local[32];
    int base = t*C;
    int s = 0;
    for (int j = 0; j < C && j < 32; ++j){
        int idx = base + j;
        int v = (idx < n) ? cnt[idx] : 0;
        local[j] = s; s += v;
    }
    part[t] = s;
    __syncthreads();
    for (int off = 1; off < 1024; off <<= 1){
        int v = (t >= off) ? part[t-off] : 0;
        __syncthreads();
        part[t] += v;
        __syncthreads();
    }
    int pre = (t == 0) ? 0 : part[t-1];
    for (int j = 0; j < C && j < 32; ++j){
        int idx = base + j;
        if (idx < n){ int rs = pre + local[j]; row_start[idx] = rs; cursor[idx] = rs; }
    }
    if (t == 0) row_start[n] = E;
}

// ---------------- scatter edge ids into sorted order ----------------
__global__ void scatter_kernel(const int* __restrict__ edst, int* __restrict__ cursor,
                               int* __restrict__ perm, int E){
    int e = blockIdx.x*blockDim.x + threadIdx.x;
    if (e < E){ int p = atomicAdd(&cursor[edst[e]], 1); perm[p] = e; }
}

__global__ void isd_kernel(const int* __restrict__ cnt, float* __restrict__ isd, int n){
    int i = blockIdx.x*blockDim.x + threadIdx.x;
    if (i < n) isd[i] = rsqrtf((float)cnt[i]);   // deg >= 1 (self loops)
}

// ---------------- node pre-transform (f_s, sc_s, f_v, sc_v) ----------------
template<int OS>
__global__ void node_pre(const float* __restrict__ s, int ss,
                         const float* __restrict__ v, int vs,
                         const float* __restrict__ attr,
                         const float* __restrict__ Wl1s, const float* __restrict__ Wscs,
                         const float* __restrict__ Wl1v, const float* __restrict__ Wscv,
                         float* __restrict__ f_s, float* __restrict__ sc_s,
                         float* __restrict__ f_v, float* __restrict__ sc_v, int n_nodes)
{
    constexpr int TOT = 64 + OS + 96 + 96;
    int t = blockIdx.x*blockDim.x + threadIdx.x;
    if (t >= n_nodes*TOT) return;
    int n = t / TOT, r = t - n*TOT;
    float a = attr[n];
    const float* srow = s + (size_t)n*ss;
    const float* vrow = v + (size_t)n*vs;

    if (r < 64 + OS){
        float acc = 0.f;
        if (r < 64){
            const float* col = Wl1s + r;
            #pragma unroll 8
            for (int k = 0; k < 64; ++k) acc += srow[k]*col[k*64];
            f_s[(size_t)n*64 + r] = acc * a * INV8;
        } else {
            int j = r - 64;
            const float* col = Wscs + j;
            #pragma unroll 8
            for (int k = 0; k < 64; ++k) acc += srow[k]*col[k*OS];
            sc_s[(size_t)n*OS + j] = acc * a * INV8;
        }
    } else {
        int q = r - (64 + OS);
        bool first = (q < 96);
        if (!first) q -= 96;
        int w = q/3, c = q - 3*w;
        const float* W = first ? Wl1v : Wscv;
        float acc = 0.f;
        #pragma unroll 8
        for (int u = 0; u < 32; ++u) acc += vrow[u*3 + c]*W[u*32 + w];
        float* op = (first ? f_v : sc_v) + (size_t)n*96 + q;
        *op = acc * a * INV_SQRT32;
    }
}

// ---------------- edge MLP: per sorted slot, write w (192 fp16) ----------------
__global__ __launch_bounds__(256, 2) void edge_mlp(
    const int* __restrict__ perm, const float* __restrict__ escal,
    const float* __restrict__ Wfa, const float* __restrict__ Wfb,
    __half* __restrict__ wbuf, int E)
{
    __shared__ __align__(16) float lds[CS*FCH + WN*FCH];  // 64 KB
    const int tid = threadIdx.x;
    // WfaT[j][k] = Wfa[k][j]: lane-consecutive k -> conflict-free LDS writes
    for (int i = tid; i < 64*64; i += 256){ int j = i >> 6, k = i & 63; lds[j*64 + k] = Wfa[k*64 + j]; }
    for (int i = tid; i < 192*64; i += 256){ int o = i >> 6, k = i & 63; lds[4096 + o*64 + k] = Wfb[k*192 + o]; }
    __syncthreads();

    const int i = blockIdx.x*256 + tid;
    if (i >= E) return;
    const int e = perm[i];

    float4 es[16];
    {
        const float4* p = reinterpret_cast<const float4*>(escal + (size_t)e*CS);
        #pragma unroll
        for (int k = 0; k < 16; ++k) es[k] = p[k];
    }

    float h[FCH];
    #pragma unroll
    for (int j = 0; j < FCH; ++j){
        const float4* wr = reinterpret_cast<const float4*>(&lds[j*FCH]);
        float ax=0.f, ay=0.f, az=0.f, aw=0.f;
        #pragma unroll
        for (int k = 0; k < 16; ++k){
            float4 w = wr[k];
            ax += es[k].x*w.x; ay += es[k].y*w.y; az += es[k].z*w.z; aw += es[k].w*w.w;
        }
        h[j] = siluf(((ax+ay)+(az+aw)) * INV8);
    }

    const float* wfb = &lds[CS*FCH];
    __half* wp = wbuf + (size_t)i*WN;

    #pragma unroll 2
    for (int o = 0; o < WN; o += 4){
        float wq[4];
        #pragma unroll
        for (int j = 0; j < 4; ++j){
            const float4* wr = reinterpret_cast<const float4*>(&wfb[(o+j)*FCH]);
            float ax=0.f, ay=0.f, az=0.f, aw=0.f;
            #pragma unroll
            for (int k = 0; k < 16; ++k){
                float4 w = wr[k];
                ax += h[4*k+0]*w.x; ay += h[4*k+1]*w.y; az += h[4*k+2]*w.z; aw += h[4*k+3]*w.w;
            }
            wq[j] = ((ax+ay)+(az+aw)) * INV8;
        }
        union { __half2 h2[2]; uint2 u; } pk;
        pk.h2[0] = __floats2half2_rn(wq[0], wq[1]);
        pk.h2[1] = __floats2half2_rn(wq[2], wq[3]);
        *reinterpret_cast<uint2*>(wp + o) = pk.u;
    }
}

// ---------------- aggregation + fused node post ----------------
// block = node. Aggregation phase: 384 threads = 384 mid channels:
//   t in [0,64)   : agg_s[t]        (w00 path)
//   t in [64,96)  : agg_s[64+u]     (w11 path, u=t-64)
//   t in [96,384) : agg_v[u3][cc]   (q=t-96, u3=q/3, cc=q%3; u3<64: w01, u3>=64: w10)
// Post phase: t in [0,OS) -> out_s; t in [96,192) -> out_v[ww][cc], ww=(t-96)/3.
template<int OS, bool FINAL>
__global__ __launch_bounds__(384) void agg_post(
    const int* __restrict__ row_start, const int* __restrict__ perm,
    const int* __restrict__ esrc, const float* __restrict__ eattr,
    const __half* __restrict__ wbuf,
    const float* __restrict__ f_s, const float* __restrict__ f_v,
    const float* __restrict__ isd, const float* __restrict__ attr,
    const float* __restrict__ sc_s, const float* __restrict__ sc_v,
    const float* __restrict__ W2s, const float* __restrict__ W2v,
    const float* __restrict__ W3,
    float* __restrict__ out_s, float* __restrict__ out_v)
{
    const int n = blockIdx.x;
    const int t = threadIdx.x;
    const int rs = row_start[n], re = row_start[n+1];

    // aggregation role decode
    int q = t - 96, u3 = 0, cc = 0;
    if (t >= 96){ u3 = q/3; cc = q - 3*u3; }

    float acc = 0.f;
    for (int i = rs; i < re; ++i){
        const int e = perm[i];
        const __half* wr = wbuf + (size_t)i*WN;
        const float* ea = eattr + (size_t)e*4;
        const int src = esrc[e];
        if (t < 64){
            acc += __half2float(wr[t]) * f_s[(size_t)src*64 + t] * ea[0];
        } else if (t < 96){
            int u = t - 64;
            const float* fv = f_v + (size_t)src*96 + u*3;
            float dv = fv[0]*ea[1] + fv[1]*ea[2] + fv[2]*ea[3];
            acc += __half2float(wr[160+u]) * dv * INV_SQRT3;
        } else if (u3 < 64){
            acc += __half2float(wr[64+u3]) * f_s[(size_t)src*64 + u3] * ea[1+cc];
        } else {
            acc += __half2float(wr[128+(u3-64)]) * f_v[(size_t)src*96 + (u3-64)*3 + cc] * ea[0];
        }
    }
    acc *= isd[n];

    __shared__ float asd[96], avd[288], hsl[96];
    if (t < 96) asd[t] = acc; else avd[q] = acc;
    __syncthreads();

    const float a = attr[n];
    float ang = 0.f;
    #pragma unroll 8
    for (int k = 0; k < 96; ++k) ang += asd[k]*W3[k];
    ang *= 0.1f * a * INV_SQRT96;
    const float c_ = cosf(ang), s_ = sinf(ang);

    // ---- output phase (192 active threads) ----
    float hv = 0.f;
    if (t < OS){
        float d = 0.f;
        #pragma unroll 8
        for (int k = 0; k < 96; ++k) d += asd[k]*W2s[k*OS + t];
        float hs = c_*sc_s[(size_t)n*OS + t] + s_*(d * a * INV_SQRT96);
        if (FINAL) out_s[(size_t)n*160 + t] = hs;
        else       hsl[t] = hs;
    }
    if (t >= 96 && t < 192){
        const int q2 = t - 96;            // [0,96): output vector channel
        const int ww = q2/3, c2 = q2 - 3*ww;
        float d = 0.f;
        #pragma unroll 8
        for (int k = 0; k < 96; ++k) d += avd[k*3 + c2]*W2v[k*32 + ww];
        hv = c_*sc_v[(size_t)n*96 + q2] + s_*(d * a * INV_SQRT96);
        if (FINAL) out_s[(size_t)n*160 + 64 + q2] = hv;
    }
    if (!FINAL){
        __syncthreads();
        if (t < 64) out_s[(size_t)n*64 + t] = siluf(hsl[t]);
        if (t >= 96 && t < 192){
            const int q2 = t - 96;
            const int ww = q2/3;
            float sg = 1.f / (1.f + __expf(-hsl[64 + ww]));
            out_v[(size_t)n*96 + q2] = sg * hv;
        }
    }
}

// ---------------- launch ----------------
extern "C" void kernel_launch(void* const* d_in, const int* in_sizes, int n_in,
                              void* d_out, int out_size, void* d_ws, size_t ws_size,
                              hipStream_t stream)
{
    const float* nf    = (const float*)d_in[0];
    const float* nattr = (const float*)d_in[1];
    const int*   esrc  = (const int*)  d_in[2];
    const int*   edst  = (const int*)  d_in[3];
    const float* eattr = (const float*)d_in[4];
    const float* escal = (const float*)d_in[5];
    const float* p1_sc_s = (const float*)d_in[6];
    const float* p1_sc_v = (const float*)d_in[7];
    const float* p1_l1_s = (const float*)d_in[8];
    const float* p1_l1_v = (const float*)d_in[9];
    const float* p1_fa   = (const float*)d_in[10];
    const float* p1_fb   = (const float*)d_in[11];
    const float* p1_l2_s = (const float*)d_in[12];
    const float* p1_l2_v = (const float*)d_in[13];
    const float* p1_l3   = (const float*)d_in[14];
    const float* p2_sc_s = (const float*)d_in[15];
    const float* p2_sc_v = (const float*)d_in[16];
    const float* p2_l1_s = (const float*)d_in[17];
    const float* p2_l1_v = (const float*)d_in[18];
    const float* p2_fa   = (const float*)d_in[19];
    const float* p2_fb   = (const float*)d_in[20];
    const float* p2_l2_s = (const float*)d_in[21];
    const float* p2_l2_v = (const float*)d_in[22];
    const float* p2_l3   = (const float*)d_in[23];

    const int N = in_sizes[1];
    const int E = in_sizes[2];

    // ---- workspace layout ----
    char* wsb = (char*)d_ws;
    int* cnt       = (int*)wsb;                     wsb += (size_t)N*4;
    int* row_start = (int*)wsb;                     wsb += (size_t)(N+1)*4;
    int* cursor    = (int*)wsb;                     wsb += (size_t)N*4;
    int* perm      = (int*)wsb;                     wsb += (size_t)E*4;
    float* isd     = (float*)wsb;                   wsb += (size_t)N*4;
    float* fs      = (float*)wsb;                   wsb += (size_t)N*64*4;
    float* fv      = (float*)wsb;                   wsb += (size_t)N*96*4;
    float* scs     = (float*)wsb;                   wsb += (size_t)N*96*4;
    float* scv     = (float*)wsb;                   wsb += (size_t)N*96*4;
    float* gs      = (float*)wsb;                   wsb += (size_t)N*64*4;
    float* gv      = (float*)wsb;                   wsb += (size_t)N*96*4;
    __half* wbuf   = (__half*)wsb;                  wsb += (size_t)E*WN*2;
    // total ~166 MB

    // ---- sort edges by dst ----
    hipMemsetAsync(cnt, 0, (size_t)N*4, stream);
    hist_kernel<<<(E+255)/256, 256, 0, stream>>>(edst, cnt, E);
    scan_kernel<<<1, 1024, 0, stream>>>(cnt, row_start, cursor, N, E);
    scatter_kernel<<<(E+255)/256, 256, 0, stream>>>(edst, cursor, perm, E);
    isd_kernel<<<(N+255)/256, 256, 0, stream>>>(cnt, isd, N);

    // ---- conv1 ----
    {
        int tot = N*352;
        node_pre<96><<<(tot+255)/256, 256, 0, stream>>>(nf, 160, nf+64, 160, nattr,
            p1_l1_s, p1_sc_s, p1_l1_v, p1_sc_v, fs, scs, fv, scv, N);
    }
    edge_mlp<<<(E+255)/256, 256, 0, stream>>>(perm, escal, p1_fa, p1_fb, wbuf, E);
    agg_post<96, false><<<N, 384, 0, stream>>>(row_start, perm, esrc, eattr, wbuf,
        fs, fv, isd, nattr, scs, scv, p1_l2_s, p1_l2_v, p1_l3, gs, gv);

    // ---- conv2 ----
    {
        int tot = N*320;
        node_pre<64><<<(tot+255)/256, 256, 0, stream>>>(gs, 64, gv, 96, nattr,
            p2_l1_s, p2_sc_s, p2_l1_v, p2_sc_v, fs, scs, fv, scv, N);
    }
    edge_mlp<<<(E+255)/256, 256, 0, stream>>>(perm, escal, p2_fa, p2_fb, wbuf, E);
    agg_post<64, true><<<N, 384, 0, stream>>>(row_start, perm, esrc, eattr, wbuf,
        fs, fv, isd, nattr, scs, scv, p2_l2_s, p2_l2_v, p2_l3, (float*)d_out, nullptr);
}